// Round 1
// baseline (79.993 us; speedup 1.0000x reference)
//
#include <hip/hip_runtime.h>
#include <hip/hip_bf16.h>

// LDPC normalized min-sum decoder.
// B=8 batches, M=1024 check rows, N=2048 variable cols, ~8 edges/row (E ~ 8230).
// Strategy: build sparse CSR from dense H each launch (deterministic), then
// decode fully in LDS with one block per batch (no global sync needed).

#define M_CHECK 1024
#define N_VAR   2048
#define BATCH   8
#define MAXD    12              // max check-row degree we support (actual: 8..~10)
#define CMAX    32              // max variable-col degree we support (actual mean 4)
#define EMAX    (M_CHECK*MAXD + 16)   // LDS cv capacity (12288+16 floats = ~48KB)
#define NUM_ITERS 5

// ---------------------------------------------------------------------------
// Kernel A: wave-per-row ordered compaction of H -> row_cols/deg. Also zeros
// col_cnt. Deterministic (ballot+popcount rank preserves column order).
__global__ __launch_bounds__(256) void build_rows_kernel(
    const int* __restrict__ H, int* __restrict__ deg,
    int* __restrict__ row_cols, int* __restrict__ col_cnt)
{
    int gtid = blockIdx.x * 256 + threadIdx.x;
    if (gtid < N_VAR) col_cnt[gtid] = 0;

    int m    = blockIdx.x * 4 + (threadIdx.x >> 6);   // 4 waves/block, wave per row
    int lane = threadIdx.x & 63;
    int base = 0;
    for (int c = 0; c < N_VAR; c += 64) {
        int j = c + lane;
        int h = H[m * N_VAR + j];                     // coalesced 256B per wave
        unsigned long long mask = __ballot(h != 0);
        if (h != 0) {
            int pos = base + __popcll(mask & ((1ULL << lane) - 1ULL));
            if (pos < MAXD) row_cols[m * MAXD + pos] = j;
        }
        base += __popcll(mask);
    }
    if (lane == 0) deg[m] = (base < MAXD) ? base : MAXD;
}

// ---------------------------------------------------------------------------
// Kernel B: exclusive prefix sum of deg[1024] -> row_ptr[0..M] (single block).
__global__ __launch_bounds__(1024) void scan_kernel(
    const int* __restrict__ deg, int* __restrict__ row_ptr)
{
    __shared__ int s[M_CHECK];
    int t = threadIdx.x;
    s[t] = deg[t];
    __syncthreads();
    for (int off = 1; off < M_CHECK; off <<= 1) {
        int x = (t >= off) ? s[t - off] : 0;
        __syncthreads();
        s[t] += x;
        __syncthreads();
    }
    row_ptr[t + 1] = s[t];          // inclusive at t -> exclusive at t+1
    if (t == 0) row_ptr[0] = 0;
}

// ---------------------------------------------------------------------------
// Kernel C1: scatter edges into column lists (atomic append; order fixed later).
__global__ __launch_bounds__(256) void build_cols_kernel(
    const int* __restrict__ deg, const int* __restrict__ row_ptr,
    const int* __restrict__ row_cols, int* __restrict__ col_cnt,
    int* __restrict__ col_edge)
{
    int m = blockIdx.x * 256 + threadIdx.x;
    if (m >= M_CHECK) return;
    int base = row_ptr[m], dm = deg[m];
    for (int d = 0; d < dm; ++d) {
        int col = row_cols[m * MAXD + d];
        int pos = atomicAdd(&col_cnt[col], 1);
        if (pos < CMAX) col_edge[col * CMAX + pos] = base + d;
    }
}

// ---------------------------------------------------------------------------
// Kernel C2: per-column insertion sort of edge ids -> deterministic gather order.
__global__ __launch_bounds__(256) void sort_cols_kernel(
    int* __restrict__ col_cnt, int* __restrict__ col_edge)
{
    int n = blockIdx.x * 256 + threadIdx.x;
    if (n >= N_VAR) return;
    int cnt = col_cnt[n];
    if (cnt > CMAX) { cnt = CMAX; col_cnt[n] = CMAX; }
    int e[CMAX];
    for (int k = 0; k < cnt; ++k) e[k] = col_edge[n * CMAX + k];
    for (int i = 1; i < cnt; ++i) {
        int v = e[i]; int j = i - 1;
        while (j >= 0 && e[j] > v) { e[j + 1] = e[j]; --j; }
        e[j + 1] = v;
    }
    for (int k = 0; k < cnt; ++k) col_edge[n * CMAX + k] = e[k];
}

// ---------------------------------------------------------------------------
// Kernel D: full decode, one block per batch, all state in LDS.
__global__ __launch_bounds__(1024) void decode_kernel(
    const float* __restrict__ soft_input, const float* __restrict__ check_weight,
    const int* __restrict__ deg, const int* __restrict__ row_ptr,
    const int* __restrict__ row_cols, const int* __restrict__ col_cnt,
    const int* __restrict__ col_edge, float* __restrict__ out)
{
    __shared__ float cv[EMAX];        // edge messages, compact CSR order
    __shared__ float colsum[N_VAR];

    const int b = blockIdx.x;
    const int t = threadIdx.x;
    const int E = row_ptr[M_CHECK];
    const float alpha = log1pf(expf(check_weight[0]));   // softplus(w)

    for (int e2 = t; e2 < E; e2 += 1024) cv[e2] = 0.f;

    // This thread's two columns (registers, not LDS)
    const int n0 = t, n1 = t + 1024;
    const float soft0 = soft_input[b * N_VAR + n0];
    const float soft1 = soft_input[b * N_VAR + n1];
    const int c0 = min(col_cnt[n0], CMAX);
    const int c1 = min(col_cnt[n1], CMAX);

    // This thread's row (one row per thread)
    const int m = t;
    const int base = row_ptr[m];
    const int dm = deg[m];
    int cols[MAXD];
#pragma unroll
    for (int d = 0; d < MAXD; ++d)
        cols[d] = (d < dm) ? row_cols[m * MAXD + d] : 0;

    __syncthreads();

    for (int it = 0; it < NUM_ITERS; ++it) {
        // --- variable-to-check totals: colsum[n] = soft[n] + sum(cv in column n)
        float s0 = soft0;
        for (int k = 0; k < c0; ++k) s0 += cv[col_edge[n0 * CMAX + k]];
        colsum[n0] = s0;
        float s1 = soft1;
        for (int k = 0; k < c1; ++k) s1 += cv[col_edge[n1 * CMAX + k]];
        colsum[n1] = s1;
        __syncthreads();

        // --- check update: min/submin + sign product over this row's edges
        float mn1 = 1e38f, mn2 = 1e38f, sprod = 1.f;
        float vcs[MAXD];
#pragma unroll
        for (int d = 0; d < MAXD; ++d) {
            float vc = 0.f;
            if (d < dm) vc = colsum[cols[d]] - cv[base + d];
            vcs[d] = vc;
            if (d < dm) {
                float a = fminf(fabsf(vc), 1e30f);
                if (a < mn1) { mn2 = mn1; mn1 = a; }
                else if (a < mn2) { mn2 = a; }
                sprod *= (vc > 0.f) ? 1.f : ((vc < 0.f) ? -1.f : 0.f);
            }
        }
#pragma unroll
        for (int d = 0; d < MAXD; ++d) {
            if (d < dm) {
                float vc = vcs[d];
                float a = fminf(fabsf(vc), 1e30f);
                float res = (a > mn1) ? mn1 : mn2;    // exclude-self min
                float sg = (vc > 0.f) ? 1.f : ((vc < 0.f) ? -1.f : 0.f);
                cv[base + d] = res * (sprod * sg) * alpha;
            }
        }
        __syncthreads();
    }

    // --- posterior LLRs
    float s0 = soft0;
    for (int k = 0; k < c0; ++k) s0 += cv[col_edge[n0 * CMAX + k]];
    out[b * N_VAR + n0] = s0;
    float s1 = soft1;
    for (int k = 0; k < c1; ++k) s1 += cv[col_edge[n1 * CMAX + k]];
    out[b * N_VAR + n1] = s1;
}

// ---------------------------------------------------------------------------
extern "C" void kernel_launch(void* const* d_in, const int* in_sizes, int n_in,
                              void* d_out, int out_size, void* d_ws, size_t ws_size,
                              hipStream_t stream)
{
    const float* soft_input   = (const float*)d_in[0];
    const float* check_weight = (const float*)d_in[1];
    const int*   H            = (const int*)d_in[2];
    float*       out          = (float*)d_out;

    int* w        = (int*)d_ws;
    int* deg      = w;                          // M
    int* row_ptr  = deg + M_CHECK;              // M+1
    int* row_cols = row_ptr + M_CHECK + 1;      // M*MAXD
    int* col_cnt  = row_cols + M_CHECK * MAXD;  // N
    int* col_edge = col_cnt + N_VAR;            // N*CMAX   (total ~328 KB)

    build_rows_kernel<<<M_CHECK / 4, 256, 0, stream>>>(H, deg, row_cols, col_cnt);
    scan_kernel<<<1, M_CHECK, 0, stream>>>(deg, row_ptr);
    build_cols_kernel<<<(M_CHECK + 255) / 256, 256, 0, stream>>>(
        deg, row_ptr, row_cols, col_cnt, col_edge);
    sort_cols_kernel<<<(N_VAR + 255) / 256, 256, 0, stream>>>(col_cnt, col_edge);
    decode_kernel<<<BATCH, 1024, 0, stream>>>(
        soft_input, check_weight, deg, row_ptr, row_cols, col_cnt, col_edge, out);
}